// Round 1
// baseline (795.394 us; speedup 1.0000x reference)
//
#include <hip/hip_runtime.h>
#include <hip/hip_bf16.h>
#include <math.h>

#define BATCH 8
#define CIN   384
#define HEADS 12
#define HD    32
#define HGT   56
#define WID   56
#define HW    3136                 // 56*56
#define NPIX  (BATCH*HW)           // 25088
#define K4H   972                  // 3^4 * 12
#define NROWS (BATCH*HW*HEADS*9)   // softmax rows of length 9

// ---------------------------------------------------------------------------
// Generic pixel-major GEMM: out[m,n] = sum_k A[m,k] * Wt[n,k] (+ bias[n])
// A_LAYOUT 0: A is x in [B, K, H*W] (channel planes) ; 1: A is row-major [M, K]
// TRANS_OUT 0: out row-major [M, N] ; 1: out in [B, N, H*W]
// M = NPIX fixed, K = CIN fixed, N passed (384 or 972, ragged tiles ok)
// ---------------------------------------------------------------------------
template<int A_LAYOUT, int TRANS_OUT>
__global__ __launch_bounds__(256) void gemm_pix(
    const float* __restrict__ A,
    const float* __restrict__ Wt,
    const float* __restrict__ bias,
    float* __restrict__ outp,
    int N)
{
  __shared__ float As[32][65];   // [k][m]
  __shared__ float Bs[32][68];   // [k][n]
  const int m0 = blockIdx.x * 64;
  const int n0 = blockIdx.y * 64;
  const int tid = threadIdx.x;
  const int tm = (tid / 16) * 4;
  const int tn = (tid % 16) * 4;
  float acc[4][4] = {{0.f}};

  for (int k0 = 0; k0 < CIN; k0 += 32) {
    if (A_LAYOUT == 0) {
      // x layout: [B, K, HW]; blocks never straddle batch (3136 % 64 == 0)
      const int b   = m0 / HW;
      const int hw0 = m0 % HW;
      const float* Ab = A + (size_t)b * CIN * HW + hw0;
      int lm = tid & 63, lk0 = tid >> 6;
      #pragma unroll
      for (int kk = lk0; kk < 32; kk += 4)
        As[kk][lm] = Ab[(size_t)(k0 + kk) * HW + lm];
    } else {
      int lk = tid & 31, lm0 = tid >> 5;
      #pragma unroll
      for (int mm = lm0; mm < 64; mm += 8)
        As[lk][mm] = A[(size_t)(m0 + mm) * CIN + k0 + lk];
    }
    {
      int lk = tid & 31, ln0 = tid >> 5;
      #pragma unroll
      for (int nn = ln0; nn < 64; nn += 8) {
        int n = n0 + nn;
        Bs[lk][nn] = (n < N) ? Wt[(size_t)n * CIN + k0 + lk] : 0.f;
      }
    }
    __syncthreads();
    #pragma unroll
    for (int kk = 0; kk < 32; ++kk) {
      float a4[4], b4[4];
      #pragma unroll
      for (int i = 0; i < 4; i++) a4[i] = As[kk][tm + i];
      #pragma unroll
      for (int j = 0; j < 4; j++) b4[j] = Bs[kk][tn + j];
      #pragma unroll
      for (int i = 0; i < 4; i++)
        #pragma unroll
        for (int j = 0; j < 4; j++) acc[i][j] += a4[i] * b4[j];
    }
    __syncthreads();
  }

  #pragma unroll
  for (int i = 0; i < 4; i++) {
    int m = m0 + tm + i;
    #pragma unroll
    for (int j = 0; j < 4; j++) {
      int n = n0 + tn + j;
      if (n < N) {
        float v = acc[i][j] + (bias ? bias[n] : 0.f);
        if (TRANS_OUT) {
          int b = m / HW, hw = m % HW;
          outp[((size_t)b * N + n) * HW + hw] = v;
        } else {
          outp[(size_t)m * N + n] = v;
        }
      }
    }
  }
}

// ---------------------------------------------------------------------------
// In-place softmax over trailing 9 elements: a = softmax(a * 32^-0.5)
// attn layout: [B*HW, HEADS, 9(p), 9(q)] flattened; one thread per (row of 9)
// ---------------------------------------------------------------------------
__global__ __launch_bounds__(256) void softmax9(float* __restrict__ attn)
{
  int r = blockIdx.x * 256 + threadIdx.x;
  if (r >= NROWS) return;
  float* p = attn + (size_t)r * 9;
  const float scale = 0.17677669529663687f; // 32^-0.5
  float v[9];
  float m = -1e30f;
  #pragma unroll
  for (int q = 0; q < 9; q++) { v[q] = p[q] * scale; m = fmaxf(m, v[q]); }
  float s = 0.f;
  #pragma unroll
  for (int q = 0; q < 9; q++) { v[q] = __expf(v[q] - m); s += v[q]; }
  float inv = 1.f / s;
  #pragma unroll
  for (int q = 0; q < 9; q++) p[q] = v[q] * inv;
}

// ---------------------------------------------------------------------------
// Attention apply + fold (as gather, no atomics).
// folded[b,y,x,c] = sum_{i,j (center valid)} sum_{i',j'}
//     A[b, center=(y-i+1)*56+(x-j+1), n, p=(i,j), q=(i',j')]
//   * vproj[b, h=x+j'-j, w=y+i'-i, c]                (quirk: transposed gather)
// One block per output pixel; 384 threads = one per channel.
// ---------------------------------------------------------------------------
__global__ __launch_bounds__(384) void apply_fold(
    const float* __restrict__ attn,   // [B*HW, 12, 9, 9]
    const float* __restrict__ vproj,  // [B, H, W, C]
    float* __restrict__ folded)       // [B, H, W, C]
{
  const int pix = blockIdx.x;
  const int b = pix / HW;
  const int yx = pix % HW;
  const int y = yx / WID, x = yx % WID;

  __shared__ float Asm[HEADS * 81];   // [n][center(i,j)][q]

  const int tid = threadIdx.x;
  // stage attention rows for the 9 candidate centers (zeros if center OOB)
  for (int r = tid; r < HEADS * 9; r += 384) {
    int n = r / 9, ct = r % 9;
    int i = ct / 3, j = ct % 3;
    int hh = y - i + 1, ww = x - j + 1;
    bool valid = (hh >= 0 && hh < HGT && ww >= 0 && ww < WID);
    size_t base = valid
        ? ((((size_t)b * HW + hh * WID + ww) * HEADS + n) * 81 + ct * 9)
        : 0;
    #pragma unroll
    for (int q = 0; q < 9; q++)
      Asm[r * 9 + q] = valid ? attn[base + q] : 0.f;
  }
  __syncthreads();

  const int c = tid;
  const int n = c >> 5;

  // 5x5 vproj neighborhood: vr[a][e] = vproj[b, h=x+e-2, w=y+a-2, c]
  float vr[5][5];
  #pragma unroll
  for (int a = 0; a < 5; a++) {
    int wi = y + a - 2;
    #pragma unroll
    for (int e = 0; e < 5; e++) {
      int hi = x + e - 2;
      vr[a][e] = (wi >= 0 && wi < WID && hi >= 0 && hi < HGT)
          ? vproj[((size_t)b * HW + hi * WID + wi) * CIN + c]
          : 0.f;
    }
  }

  float acc = 0.f;
  const float* An = &Asm[n * 81];
  #pragma unroll
  for (int i = 0; i < 3; i++)
    #pragma unroll
    for (int j = 0; j < 3; j++) {
      #pragma unroll
      for (int ip = 0; ip < 3; ip++)
        #pragma unroll
        for (int jp = 0; jp < 3; jp++)
          acc += An[(i * 3 + j) * 9 + ip * 3 + jp] * vr[2 + ip - i][2 + jp - j];
    }

  folded[(size_t)pix * CIN + c] = acc;
}

// ---------------------------------------------------------------------------
extern "C" void kernel_launch(void* const* d_in, const int* in_sizes, int n_in,
                              void* d_out, int out_size, void* d_ws, size_t ws_size,
                              hipStream_t stream)
{
  const float* x  = (const float*)d_in[0];
  const float* Wv = (const float*)d_in[1];
  const float* Wa = (const float*)d_in[2];
  const float* ba = (const float*)d_in[3];
  const float* Wp = (const float*)d_in[4];
  const float* bp = (const float*)d_in[5];
  float* out = (float*)d_out;

  float* vproj  = (float*)d_ws;                       // NPIX*384 f32
  float* attn   = vproj + (size_t)NPIX * CIN;         // NPIX*972 f32
  float* folded = attn + (size_t)NPIX * K4H;          // NPIX*384 f32

  dim3 blk(256);
  // value projection: vproj[pix, c]
  gemm_pix<0, 0><<<dim3(NPIX / 64, CIN / 64), blk, 0, stream>>>(
      x, Wv, nullptr, vproj, CIN);
  // attention logits: attn[pix, 972] (+bias)
  gemm_pix<0, 0><<<dim3(NPIX / 64, (K4H + 63) / 64), blk, 0, stream>>>(
      x, Wa, ba, attn, K4H);
  // softmax over q
  softmax9<<<dim3((NROWS + 255) / 256), blk, 0, stream>>>(attn);
  // attention apply + fold (gather)
  apply_fold<<<dim3(NPIX), dim3(384), 0, stream>>>(attn, vproj, folded);
  // output projection -> [B, C, H, W] (+bias)
  gemm_pix<1, 1><<<dim3(NPIX / 64, CIN / 64), blk, 0, stream>>>(
      folded, Wp, bp, out, CIN);
}

// Round 2
// 259.754 us; speedup vs baseline: 3.0621x; 3.0621x over previous
//
#include <hip/hip_runtime.h>
#include <hip/hip_bf16.h>
#include <math.h>

#define BATCH 8
#define CIN   384
#define HEADS 12
#define HGT   56
#define WID   56
#define HW    3136                 // 56*56
#define NPIX  (BATCH*HW)           // 25088
#define K4H   972                  // 3^4 * 12
#define K4HP  1024                 // padded N for A-GEMM
#define NROWS (NPIX*HEADS*9)

typedef __bf16 bf16x8 __attribute__((ext_vector_type(8)));
typedef float f32x4 __attribute__((ext_vector_type(4)));
typedef __hip_bfloat16 hbf16;

__device__ __forceinline__ void gload_lds16(const void* g, void* l) {
  __builtin_amdgcn_global_load_lds(
      (const __attribute__((address_space(1))) void*)g,
      (__attribute__((address_space(3))) void*)l, 16, 0, 0);
}

// ---------------------------------------------------------------------------
// transpose+convert: x [B, C, HW] f32 -> xb [B*HW, C] bf16
// ---------------------------------------------------------------------------
__global__ __launch_bounds__(256) void conv_x(const float* __restrict__ x,
                                              hbf16* __restrict__ xb)
{
  __shared__ float s[32][33];
  const int b   = blockIdx.z;
  const int hw0 = blockIdx.x * 32;
  const int c0  = blockIdx.y * 32;
  const int tx = threadIdx.x & 31, ty = threadIdx.x >> 5;   // 32x8
  #pragma unroll
  for (int i = 0; i < 4; i++) {
    int c = c0 + ty + i * 8;
    s[ty + i * 8][tx] = x[((size_t)b * CIN + c) * HW + hw0 + tx]; // s[c_l][hw_l]
  }
  __syncthreads();
  #pragma unroll
  for (int i = 0; i < 4; i++) {
    int hw = hw0 + ty + i * 8;
    xb[((size_t)b * HW + hw) * CIN + c0 + tx] = __float2bfloat16(s[tx][ty + i * 8]);
  }
}

// ---------------------------------------------------------------------------
// outf [NPIX, C] f32 -> out [B, C, HW] f32 (bias already added)
// ---------------------------------------------------------------------------
__global__ __launch_bounds__(256) void trans_out(const float* __restrict__ of,
                                                 float* __restrict__ out)
{
  __shared__ float s[32][33];
  const int b   = blockIdx.z;
  const int hw0 = blockIdx.x * 32;
  const int c0  = blockIdx.y * 32;
  const int tx = threadIdx.x & 31, ty = threadIdx.x >> 5;
  #pragma unroll
  for (int i = 0; i < 4; i++) {
    int hw = hw0 + ty + i * 8;
    s[ty + i * 8][tx] = of[((size_t)b * HW + hw) * CIN + c0 + tx]; // s[hw_l][c_l]
  }
  __syncthreads();
  #pragma unroll
  for (int i = 0; i < 4; i++) {
    int c = c0 + ty + i * 8;
    out[((size_t)b * CIN + c) * HW + hw0 + tx] = s[tx][ty + i * 8];
  }
}

// ---------------------------------------------------------------------------
// weight convert (+ zero-pad rows up to rows_dst): src [rows_src, CIN] f32
// ---------------------------------------------------------------------------
__global__ __launch_bounds__(256) void conv_w(const float* __restrict__ w,
                                              hbf16* __restrict__ wb,
                                              int rows_src, int total)
{
  int i = blockIdx.x * 256 + threadIdx.x;
  if (i >= total) return;
  int n = i / CIN;
  wb[i] = (n < rows_src) ? __float2bfloat16(w[i]) : __float2bfloat16(0.f);
}

// ---------------------------------------------------------------------------
// MFMA GEMM: out[m,n] = sum_k A[m,k]*Bt[n,k] (+bias[n])
// A: [M=NPIX, 384] bf16 row-major. Bt: [Npad, 384] bf16 row-major (padded).
// out: f32 [M, NLOG] (row stride NLOG), guard n < NLOG.
// 128x128 tile, BK=32, 4 waves (2x2 of 64x64), mfma_f32_16x16x32_bf16.
// ---------------------------------------------------------------------------
template<int NLOG, int HASBIAS>
__global__ __launch_bounds__(256) void gemm_mfma(
    const hbf16* __restrict__ A_,
    const hbf16* __restrict__ Bt_,
    const float* __restrict__ bias,
    float* __restrict__ outp)
{
  __shared__ __bf16 As[128 * 32];
  __shared__ __bf16 Bs[128 * 32];
  const __bf16* A  = (const __bf16*)A_;
  const __bf16* Bt = (const __bf16*)Bt_;

  const int tid  = threadIdx.x;
  const int wave = tid >> 6, lane = tid & 63;
  const int wr = wave >> 1, wc = wave & 1;
  const int l16 = lane & 15, kg = lane >> 4;
  const int m0 = blockIdx.x * 128, n0 = blockIdx.y * 128;

  // staging coords: per pass p, thread writes LDS bytes [p*4096 + tid*16, +16)
  const int srow = tid >> 2;              // (tid*16)>>6
  const int skb  = (tid & 3) * 16;        // byte offset within 64B row

  f32x4 acc[4][4] = {};

  for (int k0 = 0; k0 < CIN; k0 += 32) {
    const char* gA = (const char*)(A  + (size_t)m0 * CIN + k0);
    const char* gB = (const char*)(Bt + (size_t)n0 * CIN + k0);
    #pragma unroll
    for (int p = 0; p < 2; p++) {
      int row = p * 64 + srow;
      gload_lds16(gA + (size_t)row * (CIN * 2) + skb,
                  (char*)As + p * 4096 + wave * 1024);
      gload_lds16(gB + (size_t)row * (CIN * 2) + skb,
                  (char*)Bs + p * 4096 + wave * 1024);
    }
    __syncthreads();

    bf16x8 af[4], bfr[4];
    #pragma unroll
    for (int mi = 0; mi < 4; mi++)
      af[mi] = *(const bf16x8*)(As + (wr * 64 + mi * 16 + l16) * 32 + kg * 8);
    #pragma unroll
    for (int ni = 0; ni < 4; ni++)
      bfr[ni] = *(const bf16x8*)(Bs + (wc * 64 + ni * 16 + l16) * 32 + kg * 8);
    #pragma unroll
    for (int mi = 0; mi < 4; mi++)
      #pragma unroll
      for (int ni = 0; ni < 4; ni++)
        acc[mi][ni] = __builtin_amdgcn_mfma_f32_16x16x32_bf16(
            af[mi], bfr[ni], acc[mi][ni], 0, 0, 0);
    __syncthreads();
  }

  #pragma unroll
  for (int mi = 0; mi < 4; mi++) {
    #pragma unroll
    for (int ni = 0; ni < 4; ni++) {
      int n = n0 + wc * 64 + ni * 16 + l16;
      if (n < NLOG) {
        float bv = HASBIAS ? bias[n] : 0.f;
        #pragma unroll
        for (int r = 0; r < 4; r++) {
          int m = m0 + wr * 64 + mi * 16 + kg * 4 + r;
          outp[(size_t)m * NLOG + n] = acc[mi][ni][r] + bv;
        }
      }
    }
  }
}

// ---------------------------------------------------------------------------
// In-place softmax over trailing 9: a = softmax(a * 32^-0.5)
// ---------------------------------------------------------------------------
__global__ __launch_bounds__(256) void softmax9(float* __restrict__ attn)
{
  int r = blockIdx.x * 256 + threadIdx.x;
  if (r >= NROWS) return;
  float* p = attn + (size_t)r * 9;
  const float scale = 0.17677669529663687f; // 32^-0.5
  float v[9];
  float m = -1e30f;
  #pragma unroll
  for (int q = 0; q < 9; q++) { v[q] = p[q] * scale; m = fmaxf(m, v[q]); }
  float s = 0.f;
  #pragma unroll
  for (int q = 0; q < 9; q++) { v[q] = __expf(v[q] - m); s += v[q]; }
  float inv = 1.f / s;
  #pragma unroll
  for (int q = 0; q < 9; q++) p[q] = v[q] * inv;
}

// ---------------------------------------------------------------------------
// Attention apply + fold (gather form), output bf16 for the P-GEMM.
// folded[b,y,x,c] = sum_{i,j (center valid)} sum_{i',j'}
//     A[b, center=(y-i+1,x-j+1), n, p=(i,j), q=(i',j')]
//   * vproj[b, h=x+j'-j, w=y+i'-i, c]            (spatial-transpose quirk)
// ---------------------------------------------------------------------------
__global__ __launch_bounds__(384) void apply_fold(
    const float* __restrict__ attn,    // [B*HW, 12, 9, 9]
    const float* __restrict__ vproj,   // [B*HW, C] (pix-major)
    hbf16* __restrict__ foldedb)       // [B*HW, C] bf16
{
  const int pix = blockIdx.x;
  const int b = pix / HW;
  const int yx = pix % HW;
  const int y = yx / WID, x = yx % WID;

  __shared__ float Asm[HEADS * 81];

  const int tid = threadIdx.x;
  for (int r = tid; r < HEADS * 9; r += 384) {
    int n = r / 9, ct = r % 9;
    int i = ct / 3, j = ct % 3;
    int hh = y - i + 1, ww = x - j + 1;
    bool valid = (hh >= 0 && hh < HGT && ww >= 0 && ww < WID);
    size_t base = valid
        ? ((((size_t)b * HW + hh * WID + ww) * HEADS + n) * 81 + ct * 9)
        : 0;
    #pragma unroll
    for (int q = 0; q < 9; q++)
      Asm[r * 9 + q] = valid ? attn[base + q] : 0.f;
  }
  __syncthreads();

  const int c = tid;
  const int n = c >> 5;

  float vr[5][5];
  #pragma unroll
  for (int a = 0; a < 5; a++) {
    int wi = y + a - 2;
    #pragma unroll
    for (int e = 0; e < 5; e++) {
      int hi = x + e - 2;
      vr[a][e] = (wi >= 0 && wi < WID && hi >= 0 && hi < HGT)
          ? vproj[((size_t)b * HW + hi * WID + wi) * CIN + c]
          : 0.f;
    }
  }

  float acc = 0.f;
  const float* An = &Asm[n * 81];
  #pragma unroll
  for (int i = 0; i < 3; i++)
    #pragma unroll
    for (int j = 0; j < 3; j++)
      #pragma unroll
      for (int ip = 0; ip < 3; ip++)
        #pragma unroll
        for (int jp = 0; jp < 3; jp++)
          acc += An[(i * 3 + j) * 9 + ip * 3 + jp] * vr[2 + ip - i][2 + jp - j];

  foldedb[(size_t)pix * CIN + c] = __float2bfloat16(acc);
}

// ---------------------------------------------------------------------------
extern "C" void kernel_launch(void* const* d_in, const int* in_sizes, int n_in,
                              void* d_out, int out_size, void* d_ws, size_t ws_size,
                              hipStream_t stream)
{
  const float* x  = (const float*)d_in[0];
  const float* Wv = (const float*)d_in[1];
  const float* Wa = (const float*)d_in[2];
  const float* ba = (const float*)d_in[3];
  const float* Wp = (const float*)d_in[4];
  const float* bp = (const float*)d_in[5];
  float* out = (float*)d_out;

  char* w = (char*)d_ws;
  const size_t ATTN_B  = (size_t)NPIX * K4H * 4;   // 97.5 MB (reused as outf)
  const size_t VPROJ_B = (size_t)NPIX * CIN * 4;   // 38.5 MB
  const size_t XB_B    = (size_t)NPIX * CIN * 2;   // 19.3 MB (reused as foldedb)
  float* attn   = (float*)w;
  float* vproj  = (float*)(w + ATTN_B);
  hbf16* xb     = (hbf16*)(w + ATTN_B + VPROJ_B);
  hbf16* wvb    = (hbf16*)(w + ATTN_B + VPROJ_B + XB_B);
  hbf16* wab    = wvb + (size_t)CIN * CIN;
  hbf16* wpb    = wab + (size_t)K4HP * CIN;
  hbf16* foldedb = xb;            // reuse: xb dead after the two input GEMMs
  float* outf    = attn;          // reuse: attn dead after apply_fold

  // 1) input transpose/convert + weight converts
  conv_x<<<dim3(HW / 32, CIN / 32, BATCH), 256, 0, stream>>>(x, xb);
  conv_w<<<dim3((CIN * CIN + 255) / 256), 256, 0, stream>>>(Wv, wvb, CIN, CIN * CIN);
  conv_w<<<dim3((K4HP * CIN + 255) / 256), 256, 0, stream>>>(Wa, wab, K4H, K4HP * CIN);
  conv_w<<<dim3((CIN * CIN + 255) / 256), 256, 0, stream>>>(Wp, wpb, CIN, CIN * CIN);

  // 2) value projection: vproj [pix, 384] f32
  gemm_mfma<CIN, 0><<<dim3(NPIX / 128, CIN / 128), 256, 0, stream>>>(
      xb, wvb, nullptr, vproj);
  // 3) attention logits: attn [pix, 972] f32 (+ba)
  gemm_mfma<K4H, 1><<<dim3(NPIX / 128, K4HP / 128), 256, 0, stream>>>(
      xb, wab, ba, attn);
  // 4) softmax over q
  softmax9<<<dim3((NROWS + 255) / 256), 256, 0, stream>>>(attn);
  // 5) attention apply + fold -> foldedb bf16
  apply_fold<<<dim3(NPIX), dim3(384), 0, stream>>>(attn, vproj, foldedb);
  // 6) output projection (+bp): outf [pix, 384] f32
  gemm_mfma<CIN, 1><<<dim3(NPIX / 128, CIN / 128), 256, 0, stream>>>(
      foldedb, wpb, bp, outf);
  // 7) transpose to [B, C, H, W]
  trans_out<<<dim3(HW / 32, CIN / 32, BATCH), 256, 0, stream>>>(outf, out);
}